// Round 8
// baseline (445.679 us; speedup 1.0000x reference)
//
#include <hip/hip_runtime.h>
#include <math.h>

#define T_STEPS 2048
#define BATCH   16
#define DIM     1024
#define NSTATE  64
#define NFIELD  256                      // per (t,b): [k_norm|v|q|g] x 64
#define PROJ_TSTRIDE (BATCH * NFIELD)    // 4096 floats per t
static constexpr float EPS = 1e-6f;

#define AS1 __attribute__((address_space(1)))
#define AS3 __attribute__((address_space(3)))

typedef _Float16 f16x8 __attribute__((ext_vector_type(8)));
typedef _Float16 f16x4 __attribute__((ext_vector_type(4)));
typedef float    f32x4 __attribute__((ext_vector_type(4)));

// ===================== cross-lane helpers =====================
template <int CTRL>
__device__ __forceinline__ float dpp_add(float x) {
    int yi = __builtin_amdgcn_update_dpp(0, __float_as_int(x), CTRL, 0xF, 0xF, true);
    return x + __int_as_float(yi);
}
// add value from lane^16 (within each 32-lane group): ds_swizzle BitMode xor=0x10
__device__ __forceinline__ float xor16_add(float x) {
    int y = __builtin_amdgcn_ds_swizzle(__float_as_int(x), 0x401F);
    return x + __int_as_float(y);
}
__device__ __forceinline__ float reduce32(float x) {
    x = dpp_add<0x121>(x); x = dpp_add<0x122>(x);
    x = dpp_add<0x124>(x); x = dpp_add<0x128>(x);
    return xor16_add(x);
}
__device__ __forceinline__ void reduce32x2(float& x, float& y) {
    x = dpp_add<0x121>(x); y = dpp_add<0x121>(y);
    x = dpp_add<0x122>(x); y = dpp_add<0x122>(y);
    x = dpp_add<0x124>(x); y = dpp_add<0x124>(y);
    x = dpp_add<0x128>(x); y = dpp_add<0x128>(y);
    x = xor16_add(x);      y = xor16_add(y);
}
__device__ __forceinline__ void reduce32x3(float& x, float& y, float& z) {
    x = dpp_add<0x121>(x); y = dpp_add<0x121>(y); z = dpp_add<0x121>(z);
    x = dpp_add<0x122>(x); y = dpp_add<0x122>(y); z = dpp_add<0x122>(z);
    x = dpp_add<0x124>(x); y = dpp_add<0x124>(y); z = dpp_add<0x124>(z);
    x = dpp_add<0x128>(x); y = dpp_add<0x128>(y); z = dpp_add<0x128>(z);
    x = xor16_add(x);      y = xor16_add(y);      z = xor16_add(z);
}
// 16-lane variants (kappa kernel keeps the old layout)
__device__ __forceinline__ void reduce16x2(float& x, float& y) {
    x = dpp_add<0x121>(x); y = dpp_add<0x121>(y);
    x = dpp_add<0x122>(x); y = dpp_add<0x122>(y);
    x = dpp_add<0x124>(x); y = dpp_add<0x124>(y);
    x = dpp_add<0x128>(x); y = dpp_add<0x128>(y);
}
__device__ __forceinline__ float dotp(const float4& u, const float4& w) {
    float t0 = u.x * w.x; t0 = fmaf(u.y, w.y, t0);
    float t1 = u.z * w.z; t1 = fmaf(u.w, w.w, t1);
    return t0 + t1;
}
__device__ __forceinline__ float dotp2(const float2& u, const float2& w) {
    return fmaf(u.y, w.y, u.x * w.x);
}

// ========================= projection GEMM (fp16 MFMA) =========================
// (unchanged from round-5 passing version)

#define PBM   128
#define KSTEP 64
#define NKS   (DIM / KSTEP)   // 16

__global__ __launch_bounds__(256) void prep_w16(
    const float* __restrict__ Wk, const float* __restrict__ Wv,
    const float* __restrict__ Wq, const float* __restrict__ Wb,
    _Float16* __restrict__ W16)
{
    const int flat = blockIdx.x * 256 + threadIdx.x;   // 16*32*64 = 32768
    const int lane = flat & 63;
    const int st   = (flat >> 6) & 31;
    const int ks   = flat >> 11;
    const int cg = st & 15, kc2 = st >> 4;
    const int col = cg * 16 + (lane & 15);
    const int field = col >> 6, wrow = col & 63;
    const float* Wf = (field == 0 ? Wk : field == 1 ? Wv : field == 2 ? Wq : Wb);
    const float* src = Wf + (size_t)wrow * DIM + ks * 64 + kc2 * 32 + (lane >> 4) * 8;
    const float4 a = *(const float4*)(src);
    const float4 b = *(const float4*)(src + 4);
    f16x8 r;
    r[0] = (_Float16)a.x; r[1] = (_Float16)a.y; r[2] = (_Float16)a.z; r[3] = (_Float16)a.w;
    r[4] = (_Float16)b.x; r[5] = (_Float16)b.y; r[6] = (_Float16)b.z; r[7] = (_Float16)b.w;
    *(f16x8*)(W16 + (size_t)flat * 8) = r;
}

__global__ __launch_bounds__(512, 1) void proj_mfma(
    const float* __restrict__ x, const _Float16* __restrict__ W16,
    const float* __restrict__ bb, float* __restrict__ proj)
{
    __shared__ _Float16 Asub[2][16][64][8];   // 16KB/buf
    __shared__ _Float16 Bsub[2][32][64][8];   // 32KB/buf

    const int tid = threadIdx.x;
    const int w = tid >> 6, wl = tid & 63;
    const int wm = w >> 2, wn = w & 3;
    const int l15 = wl & 15, lr = wl >> 4;
    const size_t mbase = (size_t)blockIdx.x * PBM;

    _Float16* const abase = &Asub[0][0][0][0];
    _Float16* const bbase = &Bsub[0][0][0][0];

    const float* asrc[4];
    int aoff[4];
    #pragma unroll
    for (int it = 0; it < 4; ++it) {
        const int fid = it * 512 + tid;
        const int row = fid >> 4, kq = (fid & 15) * 4;
        asrc[it] = x + (mbase + row) * (size_t)DIM + kq;
        aoff[it] = ((kq >> 5) * 8 + (row >> 4)) * 512
                 + ((row & 15) + ((kq >> 3) & 3) * 16) * 8
                 + (kq & 7);
    }
    const _Float16* bsrc[4];
    int boff[4];
    #pragma unroll
    for (int m = 0; m < 4; ++m) {
        const int st = w * 4 + m;
        bsrc[m] = W16 + ((size_t)st * 64 + wl) * 8;
        boff[m] = st * 512;
    }

    auto stageB = [&](int ks, int buf) {
        #pragma unroll
        for (int m = 0; m < 4; ++m) {
            const _Float16* g = bsrc[m] + (size_t)ks * 16384;
            void* lp = (char*)bbase + (size_t)(buf * 16384 + boff[m]) * 2;
            __builtin_amdgcn_global_load_lds((const AS1 void*)g, (AS3 void*)lp, 16, 0, 0);
        }
    };

    float4 h0[4], h1[4];
    auto loadA = [&](int ks, float4* h) {
        #pragma unroll
        for (int it = 0; it < 4; ++it)
            h[it] = *(const float4*)(asrc[it] + ks * KSTEP);
    };
    auto writeA = [&](const float4* h, int buf) {
        #pragma unroll
        for (int it = 0; it < 4; ++it) {
            f16x4 v;
            v[0] = (_Float16)h[it].x; v[1] = (_Float16)h[it].y;
            v[2] = (_Float16)h[it].z; v[3] = (_Float16)h[it].w;
            *(f16x4*)(abase + buf * 8192 + aoff[it]) = v;
        }
    };

    f32x4 acc[4][4] = {};

    loadA(0, h0);
    stageB(0, 0);
    loadA(1, h1);
    writeA(h0, 0);
    __syncthreads();

    #pragma unroll
    for (int ks = 0; ks < NKS; ++ks) {
        const int buf = ks & 1;
        if (ks + 1 < NKS) stageB(ks + 1, buf ^ 1);
        if (ks + 2 < NKS) loadA(ks + 2, (ks & 1) ? h1 : h0);

        #pragma unroll
        for (int kc = 0; kc < 2; ++kc) {
            f16x8 af[4], bf[4];
            #pragma unroll
            for (int mf = 0; mf < 4; ++mf)
                af[mf] = *(const f16x8*)&Asub[buf][kc * 8 + wm * 4 + mf][wl][0];
            #pragma unroll
            for (int nf = 0; nf < 4; ++nf)
                bf[nf] = *(const f16x8*)&Bsub[buf][kc * 16 + wn * 4 + nf][wl][0];
            #pragma unroll
            for (int mf = 0; mf < 4; ++mf)
                #pragma unroll
                for (int nf = 0; nf < 4; ++nf)
                    acc[mf][nf] = __builtin_amdgcn_mfma_f32_16x16x32_f16(
                        af[mf], bf[nf], acc[mf][nf], 0, 0, 0);
        }

        if (ks + 1 < NKS) writeA((ks & 1) ? h0 : h1, buf ^ 1);
        __syncthreads();
    }

    if (wn == 0) {                       // k field: row-normalize over 64 cols
        #pragma unroll
        for (int mf = 0; mf < 4; ++mf) {
            f32x4 s = acc[mf][0] * acc[mf][0];
            #pragma unroll
            for (int nf = 1; nf < 4; ++nf) s += acc[mf][nf] * acc[mf][nf];
            #pragma unroll
            for (int r = 0; r < 4; ++r) {
                float t = s[r];
                t += __shfl_xor(t, 1); t += __shfl_xor(t, 2);
                t += __shfl_xor(t, 4); t += __shfl_xor(t, 8);
                const float sc = 1.f / (sqrtf(t) + EPS);
                #pragma unroll
                for (int nf = 0; nf < 4; ++nf) acc[mf][nf][r] *= sc;
            }
        }
    }
    if (wn == 3) {                       // beta field: sigmoid(acc + bias)
        #pragma unroll
        for (int nf = 0; nf < 4; ++nf) {
            const float bv = bb[nf * 16 + l15];
            #pragma unroll
            for (int mf = 0; mf < 4; ++mf)
                #pragma unroll
                for (int r = 0; r < 4; ++r)
                    acc[mf][nf][r] = 1.f / (1.f + __expf(-(acc[mf][nf][r] + bv)));
        }
    }

    #pragma unroll
    for (int mf = 0; mf < 4; ++mf)
        #pragma unroll
        for (int r = 0; r < 4; ++r) {
            float* dst = proj + (mbase + wm * 64 + mf * 16 + lr * 4 + r) * NFIELD
                              + wn * 64 + l15;
            dst[0]  = acc[mf][0][r];
            dst[16] = acc[mf][1][r];
            dst[32] = acc[mf][2][r];
            dst[48] = acc[mf][3][r];
        }
}

// ============================ kappa/kq precompute ============================
#define KAP_T 2112

__global__ __launch_bounds__(256) void kappa_kernel(
    const float* __restrict__ proj, float* __restrict__ kap2)
{
    const int tid = threadIdx.x;
    const int gid = blockIdx.x * 16 + (tid >> 4);   // one (t,b) per 16 lanes
    const int l   = tid & 15;
    const int t = gid >> 4, b = gid & 15;
    if (t >= T_STEPS) {
        if (l == 0) *(float2*)(kap2 + (size_t)gid * 2) = make_float2(0.f, 0.f);
        return;
    }
    const float* base = proj + ((size_t)t * BATCH + b) * NFIELD;
    const float4 k0 = *(const float4*)(base + 4 * l);           // k_norm(t)
    const float4 q0 = *(const float4*)(base + 128 + 4 * l);     // q(t)
    float cp = 0.f;
    float cq = dotp(k0, q0);
    if (t + 1 < T_STEPS) {
        const float4 k1 = *(const float4*)(base + PROJ_TSTRIDE + 4 * l);
        cp = dotp(k0, k1);
    }
    reduce16x2(cp, cq);
    if (l == 0) *(float2*)(kap2 + (size_t)gid * 2) = make_float2(cp, cq);
}

// ============================ sequential scan v10 ============================
// Same exact algebra as v9 (entry-state dots + kappa/kq lookahead), but
// re-partitioned: 2 rows per wave, 32 lanes per row, 2 j-elements per lane.
//   - per-row instruction cost ~halved (S-update 4, partials 2x2, one
//     xor16 ds_swizzle finishes each reduce)
//   - the two rows' recurrences are independent chains inside one wave: ILP
//   - 512 waves (vs 256): 2x occupancy
// Staging (DMA maps, LDS layout) identical; redistributed over 4 waves.

#define CH 32
#define NCHUNK (T_STEPS / CH)

__global__ __launch_bounds__(256, 1) void scan_kernel(
    const float* __restrict__ proj,  // [T][B][256]
    const float* __restrict__ kap2,  // [KAP_T][B][2]
    const float* __restrict__ S0,    // [B][64][64]
    float* __restrict__ out,         // [T][B][64]  (silu applied at store)
    float* __restrict__ Sfin)        // [B][64][64]
{
    __shared__ float KQ[2][CH][128];   // [s][0:64)=kn, [64:128)=q   (32 KB)
    __shared__ float VG[2][CH][16];    // [s][2r]=v(i0+r), [s][2r+1]=g(i0+r)
    __shared__ float KP2[2][CH][2];    // [s] = {kap1(s), kq0(s)}

    const int tid  = threadIdx.x;         // 0..255
    const int w    = tid >> 6;            // wave 0..3
    const int wl   = tid & 63;
    const int half = wl >> 5;             // 0/1 -> which of the wave's 2 rows
    const int jl   = wl & 31;             // j-pair index within row
    const int b    = blockIdx.x >> 3;
    const int i0   = (blockIdx.x & 7) * 8;
    const int i    = i0 + 2 * w + half;   // this lane's row
    const int c0   = 2 * jl;              // j element base

    const size_t srow = ((size_t)(b * 64 + i)) * 64 + c0;
    float2 S = *(const float2*)(S0 + srow);

    const float* pb = proj + (size_t)b * NFIELD;

    // --- DMA address maps (constant per lane; same math as v9) ---
    const int l31  = wl & 31;
    const int kq_f = l31 * 4 + ((l31 >= 16) ? 64 : 0);
    const int kq_s = wl >> 5;
    const int idx  = wl & 15;
    const int vg_f = (idx & 1) ? (192 + i0 + (idx >> 1)) : (64 + i0 + (idx >> 1));
    const int vg_sl = wl >> 4;

    auto stage = [&](int c, int nb) {
        const float* cbase = pb + (size_t)c * CH * PROJ_TSTRIDE;
        #pragma unroll
        for (int m = 0; m < 4; ++m) {                    // 16 KQ insts over 4 waves
            const int n = w * 4 + m;
            const float* g = cbase + (size_t)(2 * n + kq_s) * PROJ_TSTRIDE + kq_f;
            void* lp = (char*)&KQ[nb][0][0] + n * 1024;
            __builtin_amdgcn_global_load_lds((const AS1 void*)g, (AS3 void*)lp, 16, 0, 0);
        }
        #pragma unroll
        for (int m = 0; m < 2; ++m) {                    // 8 VG insts over 4 waves
            const int p = w * 2 + m;
            const float* g = cbase + (size_t)(4 * p + vg_sl) * PROJ_TSTRIDE + vg_f;
            void* lp = (char*)&VG[nb][0][0] + p * 256;
            __builtin_amdgcn_global_load_lds((const AS1 void*)g, (AS3 void*)lp, 4, 0, 0);
        }
        if (w == 0) {                                    // {kap1,kq0} for 32 steps
            const float* g = kap2 + ((size_t)(c * CH + (wl >> 1)) * BATCH + b) * 2
                           + (wl & 1);
            void* lp = (char*)&KP2[nb][0][0];
            __builtin_amdgcn_global_load_lds((const AS1 void*)g, (AS3 void*)lp, 4, 0, 0);
        }
    };

    float2 kn_r[4], q_r[4], vg_r[4], kk_r[4];
    const int vgo = 2 * (2 * w + half);   // this lane's {v,g} offset within VG[s]

    stage(0, 0);
    __syncthreads();                     // waits DMA (vmcnt) + all threads

    float a, cqr, cpr;
    float osel = 0.f;

    for (int c = 0; c < NCHUNK; ++c) {
        const int cb = c & 1;
        const float (*KQc)[128] = KQ[cb];
        const float (*VGc)[16]  = VG[cb];
        const float (*KPc)[2]   = KP2[cb];

        auto ldslot = [&](int s, int j) {
            kn_r[j] = *(const float2*)(&KQc[s][c0]);
            q_r [j] = *(const float2*)(&KQc[s][64 + c0]);
            vg_r[j] = *(const float2*)(&VGc[s][vgo]);
            kk_r[j] = *(const float2*)(&KPc[s][0]);
        };

        // prime: slots 0..3 + a/cqr/cpr from the entry state (exact re-anchor)
        #pragma unroll
        for (int j = 0; j < 4; ++j) ldslot(j, j);
        {
            float aP  = dotp2(S, kn_r[0]);   // <S, k(0)>
            float cqP = dotp2(S, q_r[0]);    // <S, q(0)>
            float cpP = dotp2(S, kn_r[1]);   // <S, k(1)>
            reduce32x3(aP, cqP, cpP);
            a = aP; cqr = cqP; cpr = cpP;
        }

        const bool more = (c + 1 < NCHUNK);
        if (more) stage(c + 1, cb ^ 1);  // DMA in flight across this chunk

        #pragma unroll
        for (int s = 0; s < CH; ++s) {
            const int j = s & 3;

            const float2 kn = kn_r[j];
            const float  v = vg_r[j].x, g = vg_r[j].y;
            const float2 kk = kk_r[j];   // {kap1(s), kq0(s)}

            // --- consume pipelined values: pure short fma chains ---
            const float d  = v - a;
            const float sq = fmaf(d, kk.y, g * cqr);   // Sq(s), exact
            const float an = fmaf(d, kk.x, g * cpr);   // a(s+1), exact

            S.x = fmaf(d, kn.x, g * S.x);
            S.y = fmaf(d, kn.y, g * S.y);

            if (s + 4 < CH) ldslot(s + 4, j);   // refill after slot consumed

            // --- NEXT step's dots from fresh S; reduce has a full period ---
            if (s + 2 < CH) {
                float cqP = dotp2(S, q_r[(s + 1) & 3]);     // <S(s), q(s+1)>
                float cpP = dotp2(S, kn_r[(s + 2) & 3]);    // <S(s), k(s+2)>
                reduce32x2(cpP, cqP);
                cpr = cpP; cqr = cqP;
            } else if (s + 1 < CH) {                        // s == CH-2
                cqr = reduce32(dotp2(S, q_r[(s + 1) & 3]));
            }                                               // s == CH-1: re-primed
            a = an;

            osel = (s == jl) ? sq : osel;    // CH == 32: each lane keeps one t
            if (s == CH - 1) {
                const float y = osel * osel / (1.f + __expf(-osel));  // fused silu
                out[((size_t)(c * CH + jl) * BATCH + b) * 64 + i] = y;
            }
        }

        if (more) __syncthreads();       // next chunk's DMA complete
    }

    *(float2*)(Sfin + srow) = S;
}

// ================================ launch ================================
extern "C" void kernel_launch(void* const* d_in, const int* in_sizes, int n_in,
                              void* d_out, int out_size, void* d_ws, size_t ws_size,
                              hipStream_t stream) {
    const float* x  = (const float*)d_in[0];
    const float* S0 = (const float*)d_in[1];
    const float* Wk = (const float*)d_in[2];
    const float* Wv = (const float*)d_in[3];
    const float* Wq = (const float*)d_in[4];
    const float* Wb = (const float*)d_in[5];
    const float* bb = (const float*)d_in[6];

    float* out  = (float*)d_out;                               // [T][B][64]
    float* Sfin = out + (size_t)T_STEPS * BATCH * NSTATE;      // [B][64][64]

    float*    proj = (float*)d_ws;                             // 33.55 MB
    float*    kap2 = proj + (size_t)T_STEPS * BATCH * NFIELD;  // 270 KB
    _Float16* W16  = (_Float16*)(kap2 + (size_t)KAP_T * BATCH * 2); // 512 KB

    prep_w16<<<128, 256, 0, stream>>>(Wk, Wv, Wq, Wb, W16);
    proj_mfma<<<(T_STEPS * BATCH) / PBM, 512, 0, stream>>>(x, W16, bb, proj);
    kappa_kernel<<<KAP_T, 256, 0, stream>>>(proj, kap2);
    scan_kernel<<<(BATCH * NSTATE) / 8, 256, 0, stream>>>(proj, kap2, S0, out, Sfin);
}

// Round 9
// 422.049 us; speedup vs baseline: 1.0560x; 1.0560x over previous
//
#include <hip/hip_runtime.h>
#include <math.h>

#define T_STEPS 2048
#define BATCH   16
#define DIM     1024
#define NSTATE  64
#define NFIELD  256                      // per (t,b): [k_norm|v|q|g] x 64
#define PROJ_TSTRIDE (BATCH * NFIELD)    // 4096 floats per t
static constexpr float EPS = 1e-6f;

#define AS1 __attribute__((address_space(1)))
#define AS3 __attribute__((address_space(3)))

typedef _Float16 f16x8 __attribute__((ext_vector_type(8)));
typedef _Float16 f16x4 __attribute__((ext_vector_type(4)));
typedef float    f32x4 __attribute__((ext_vector_type(4)));

// ===================== cross-lane helpers =====================
// DPP multiply-with-shift for inclusive product scan (identity = 1.0 via old)
template <int CTRL>
__device__ __forceinline__ float dpp_pmul(float x) {
    int yi = __builtin_amdgcn_update_dpp(0x3f800000, __float_as_int(x),
                                         CTRL, 0xF, 0xF, false);
    return x * __int_as_float(yi);
}
// 16-lane reduce pair (mn-free kernels)
template <int CTRL>
__device__ __forceinline__ float dpp_add(float x) {
    int yi = __builtin_amdgcn_update_dpp(0, __float_as_int(x), CTRL, 0xF, 0xF, true);
    return x + __int_as_float(yi);
}

// ========================= projection GEMM (fp16 MFMA) =========================
// (unchanged from round-6 passing version)

#define PBM   128
#define KSTEP 64
#define NKS   (DIM / KSTEP)   // 16

__global__ __launch_bounds__(256) void prep_w16(
    const float* __restrict__ Wk, const float* __restrict__ Wv,
    const float* __restrict__ Wq, const float* __restrict__ Wb,
    _Float16* __restrict__ W16)
{
    const int flat = blockIdx.x * 256 + threadIdx.x;   // 16*32*64 = 32768
    const int lane = flat & 63;
    const int st   = (flat >> 6) & 31;
    const int ks   = flat >> 11;
    const int cg = st & 15, kc2 = st >> 4;
    const int col = cg * 16 + (lane & 15);
    const int field = col >> 6, wrow = col & 63;
    const float* Wf = (field == 0 ? Wk : field == 1 ? Wv : field == 2 ? Wq : Wb);
    const float* src = Wf + (size_t)wrow * DIM + ks * 64 + kc2 * 32 + (lane >> 4) * 8;
    const float4 a = *(const float4*)(src);
    const float4 b = *(const float4*)(src + 4);
    f16x8 r;
    r[0] = (_Float16)a.x; r[1] = (_Float16)a.y; r[2] = (_Float16)a.z; r[3] = (_Float16)a.w;
    r[4] = (_Float16)b.x; r[5] = (_Float16)b.y; r[6] = (_Float16)b.z; r[7] = (_Float16)b.w;
    *(f16x8*)(W16 + (size_t)flat * 8) = r;
}

__global__ __launch_bounds__(512, 1) void proj_mfma(
    const float* __restrict__ x, const _Float16* __restrict__ W16,
    const float* __restrict__ bb, float* __restrict__ proj)
{
    __shared__ _Float16 Asub[2][16][64][8];   // 16KB/buf
    __shared__ _Float16 Bsub[2][32][64][8];   // 32KB/buf

    const int tid = threadIdx.x;
    const int w = tid >> 6, wl = tid & 63;
    const int wm = w >> 2, wn = w & 3;
    const int l15 = wl & 15, lr = wl >> 4;
    const size_t mbase = (size_t)blockIdx.x * PBM;

    _Float16* const abase = &Asub[0][0][0][0];
    _Float16* const bbase = &Bsub[0][0][0][0];

    const float* asrc[4];
    int aoff[4];
    #pragma unroll
    for (int it = 0; it < 4; ++it) {
        const int fid = it * 512 + tid;
        const int row = fid >> 4, kq = (fid & 15) * 4;
        asrc[it] = x + (mbase + row) * (size_t)DIM + kq;
        aoff[it] = ((kq >> 5) * 8 + (row >> 4)) * 512
                 + ((row & 15) + ((kq >> 3) & 3) * 16) * 8
                 + (kq & 7);
    }
    const _Float16* bsrc[4];
    int boff[4];
    #pragma unroll
    for (int m = 0; m < 4; ++m) {
        const int st = w * 4 + m;
        bsrc[m] = W16 + ((size_t)st * 64 + wl) * 8;
        boff[m] = st * 512;
    }

    auto stageB = [&](int ks, int buf) {
        #pragma unroll
        for (int m = 0; m < 4; ++m) {
            const _Float16* g = bsrc[m] + (size_t)ks * 16384;
            void* lp = (char*)bbase + (size_t)(buf * 16384 + boff[m]) * 2;
            __builtin_amdgcn_global_load_lds((const AS1 void*)g, (AS3 void*)lp, 16, 0, 0);
        }
    };

    float4 h0[4], h1[4];
    auto loadA = [&](int ks, float4* h) {
        #pragma unroll
        for (int it = 0; it < 4; ++it)
            h[it] = *(const float4*)(asrc[it] + ks * KSTEP);
    };
    auto writeA = [&](const float4* h, int buf) {
        #pragma unroll
        for (int it = 0; it < 4; ++it) {
            f16x4 v;
            v[0] = (_Float16)h[it].x; v[1] = (_Float16)h[it].y;
            v[2] = (_Float16)h[it].z; v[3] = (_Float16)h[it].w;
            *(f16x4*)(abase + buf * 8192 + aoff[it]) = v;
        }
    };

    f32x4 acc[4][4] = {};

    loadA(0, h0);
    stageB(0, 0);
    loadA(1, h1);
    writeA(h0, 0);
    __syncthreads();

    #pragma unroll
    for (int ks = 0; ks < NKS; ++ks) {
        const int buf = ks & 1;
        if (ks + 1 < NKS) stageB(ks + 1, buf ^ 1);
        if (ks + 2 < NKS) loadA(ks + 2, (ks & 1) ? h1 : h0);

        #pragma unroll
        for (int kc = 0; kc < 2; ++kc) {
            f16x8 af[4], bf[4];
            #pragma unroll
            for (int mf = 0; mf < 4; ++mf)
                af[mf] = *(const f16x8*)&Asub[buf][kc * 8 + wm * 4 + mf][wl][0];
            #pragma unroll
            for (int nf = 0; nf < 4; ++nf)
                bf[nf] = *(const f16x8*)&Bsub[buf][kc * 16 + wn * 4 + nf][wl][0];
            #pragma unroll
            for (int mf = 0; mf < 4; ++mf)
                #pragma unroll
                for (int nf = 0; nf < 4; ++nf)
                    acc[mf][nf] = __builtin_amdgcn_mfma_f32_16x16x32_f16(
                        af[mf], bf[nf], acc[mf][nf], 0, 0, 0);
        }

        if (ks + 1 < NKS) writeA((ks & 1) ? h0 : h1, buf ^ 1);
        __syncthreads();
    }

    if (wn == 0) {                       // k field: row-normalize over 64 cols
        #pragma unroll
        for (int mf = 0; mf < 4; ++mf) {
            f32x4 s = acc[mf][0] * acc[mf][0];
            #pragma unroll
            for (int nf = 1; nf < 4; ++nf) s += acc[mf][nf] * acc[mf][nf];
            #pragma unroll
            for (int r = 0; r < 4; ++r) {
                float t = s[r];
                t += __shfl_xor(t, 1); t += __shfl_xor(t, 2);
                t += __shfl_xor(t, 4); t += __shfl_xor(t, 8);
                const float sc = 1.f / (sqrtf(t) + EPS);
                #pragma unroll
                for (int nf = 0; nf < 4; ++nf) acc[mf][nf][r] *= sc;
            }
        }
    }
    if (wn == 3) {                       // beta field: sigmoid(acc + bias)
        #pragma unroll
        for (int nf = 0; nf < 4; ++nf) {
            const float bv = bb[nf * 16 + l15];
            #pragma unroll
            for (int mf = 0; mf < 4; ++mf)
                #pragma unroll
                for (int r = 0; r < 4; ++r)
                    acc[mf][nf][r] = 1.f / (1.f + __expf(-(acc[mf][nf][r] + bv)));
        }
    }

    #pragma unroll
    for (int mf = 0; mf < 4; ++mf)
        #pragma unroll
        for (int r = 0; r < 4; ++r) {
            float* dst = proj + (mbase + wm * 64 + mf * 16 + lr * 4 + r) * NFIELD
                              + wn * 64 + l15;
            dst[0]  = acc[mf][0][r];
            dst[16] = acc[mf][1][r];
            dst[32] = acc[mf][2][r];
            dst[48] = acc[mf][3][r];
        }
}

// ============================ M/N gram precompute ============================
// Per (b, chunk): Mcol[u][t] = <k_t, k_u> (0 unless t<u),
//                 Ncol[u][t] = <k_t, q_u> (0 unless t<=u).
// Layout: MN[((b*64+ch)*32 + u)*64 + {0..31 = Mcol, 32..63 = Ncol}]

#define CH 32
#define NCHUNK (T_STEPS / CH)   // 64

__global__ __launch_bounds__(256) void mn_prep(
    const float* __restrict__ proj, float* __restrict__ MN)
{
    __shared__ float K[32][68], Q[32][68];
    const int bch = blockIdx.x;            // 0..1023
    const int b = bch >> 6, ch = bch & 63;
    const int tid = threadIdx.x;

    {   // stage K (k_norm) and Q rows: coalesced
        const int t0 = tid >> 3, pp = tid & 7;
        const float* base = proj + ((size_t)(ch * 32 + t0) * BATCH + b) * NFIELD;
        *(float4*)&K[t0][8 * pp]     = *(const float4*)(base + 8 * pp);
        *(float4*)&K[t0][8 * pp + 4] = *(const float4*)(base + 8 * pp + 4);
        *(float4*)&Q[t0][8 * pp]     = *(const float4*)(base + 128 + 8 * pp);
        *(float4*)&Q[t0][8 * pp + 4] = *(const float4*)(base + 128 + 8 * pp + 4);
    }
    __syncthreads();

    const int t = tid & 31, ub = tid >> 5;   // entry row t, u-block ub
    float mm[4] = {0.f, 0.f, 0.f, 0.f}, nn[4] = {0.f, 0.f, 0.f, 0.f};
    #pragma unroll 4
    for (int db = 0; db < 16; ++db) {
        const float4 kt = *(const float4*)&K[t][4 * db];
        #pragma unroll
        for (int uu = 0; uu < 4; ++uu) {
            const float4 ku = *(const float4*)&K[ub * 4 + uu][4 * db];
            const float4 qu = *(const float4*)&Q[ub * 4 + uu][4 * db];
            mm[uu] = fmaf(kt.x, ku.x, fmaf(kt.y, ku.y,
                     fmaf(kt.z, ku.z, fmaf(kt.w, ku.w, mm[uu]))));
            nn[uu] = fmaf(kt.x, qu.x, fmaf(kt.y, qu.y,
                     fmaf(kt.z, qu.z, fmaf(kt.w, qu.w, nn[uu]))));
        }
    }
    float* dstb = MN + ((size_t)bch * 32) * 64;
    #pragma unroll
    for (int uu = 0; uu < 4; ++uu) {
        const int u = ub * 4 + uu;
        dstb[(size_t)u * 64 + t]      = (t < u)  ? mm[uu] : 0.f;
        dstb[(size_t)u * 64 + 32 + t] = (t <= u) ? nn[uu] : 0.f;
    }
}

// ============================ scan v11: chunked forward-substitution ============================
// Divide the recurrence by the per-row cumulative gate product P_t:
//   shat_t = shat_{t-1} + e_t k_t,  e_t = d_t / P_t
//   a_t = P_{t-1} (  <s0,k_t>  + sum_{u<t} e_u M[u][t] )
//   out_t = P_t ( <s0,q_t> + sum_{u<=t} e_u N[u][t] );  s_C = P_31 (s0 + sum e_u k_u)
// Lane u <- timestep u of the chunk; M/N columns live in registers (zero-padded
// so no masking is needed). Serial core = 32-step forward substitution with a
// single swizzle-broadcast per step; NO cross-lane reduce on the chain.
// Groups of 32 lanes own one row r; 2 groups/wave, 8 rows/block, 128 blocks.

__global__ __launch_bounds__(256, 1) void scan_kernel(
    const float* __restrict__ proj,  // [T][B][256]
    const float* __restrict__ MN,    // [b][ch][u][64]
    const float* __restrict__ S0,    // [B][64][64]
    float* __restrict__ out,         // [T][B][64]
    float* __restrict__ Sfin)        // [B][64][64]
{
    __shared__ float KQ[2][CH][128];   // [s][0:64)=kn, [64:128)=q  (swizzled, 32 KB)
    __shared__ float VGT[2][16][CH];   // rows 0-7 = v(row), 8-15 = g(row)  (4 KB)
    __shared__ float SROW[8][64];      // per-group state row (2 KB)

    const int tid  = threadIdx.x;         // 0..255
    const int w    = tid >> 6, wl = tid & 63;
    const int half = wl >> 5, u = wl & 31;
    const int gid  = 2 * w + half;        // group/row 0..7
    const int b    = blockIdx.x >> 3;
    const int i0   = (blockIdx.x & 7) * 8;
    const int i    = i0 + gid;

    {   // initial state row into LDS (group-private)
        const float2 s2 = *(const float2*)(S0 + ((size_t)(b * 64 + i)) * 64 + 2 * u);
        *(float2*)&SROW[gid][2 * u] = s2;
    }

    const float* pb = proj + (size_t)b * NFIELD;

    // --- DMA maps ---
    const int l31 = wl & 31;
    const int glq = wl & 15;             // granule within half
    const int hlf = (l31 >= 16);
    auto stage = [&](int c2, int nb) {
        const float* cbase = pb + (size_t)c2 * CH * PROJ_TSTRIDE;
        #pragma unroll
        for (int m = 0; m < 4; ++m) {    // KQ: 16 insts over 4 waves, 16B each
            const int n = w * 4 + m;
            const int s = 2 * n + (wl >> 5);
            const int field = (hlf ? 128 : 0) + 4 * (glq ^ (s & 7));  // XOR-swizzled src
            const float* g = cbase + (size_t)s * PROJ_TSTRIDE + field;
            void* lp = (char*)&KQ[nb][0][0] + n * 1024;
            __builtin_amdgcn_global_load_lds((const AS1 void*)g, (AS3 void*)lp, 16, 0, 0);
        }
        #pragma unroll
        for (int m = 0; m < 2; ++m) {    // VGT: 8 insts over 4 waves, 4B each
            const int p = w * 2 + m;
            const int f = 2 * p + (wl >> 5);
            const int col = wl & 31;
            const int field = (f < 8) ? (64 + i0 + f) : (192 + i0 + (f - 8));
            const float* g = cbase + (size_t)col * PROJ_TSTRIDE + field;
            void* lp = (char*)&VGT[nb][0][0] + p * 256;
            __builtin_amdgcn_global_load_lds((const AS1 void*)g, (AS3 void*)lp, 4, 0, 0);
        }
    };

    stage(0, 0);
    __syncthreads();

    for (int c = 0; c < NCHUNK; ++c) {
        const int cb = c & 1;
        if (c + 1 < NCHUNK) stage(c + 1, cb ^ 1);

        const float (*KQc)[128] = KQ[cb];
        const float (*VGTc)[CH] = VGT[cb];

        // --- M/N columns -> registers (issued early; L2/L3-resident) ---
        float Mreg[32], Nreg[32];
        {
            const float* mnb = MN + (((size_t)b * NCHUNK + c) * 32 + u) * 64;
            #pragma unroll
            for (int k = 0; k < 8; ++k) {
                const float4 t4 = *(const float4*)(mnb + 4 * k);
                Mreg[4 * k] = t4.x; Mreg[4 * k + 1] = t4.y;
                Mreg[4 * k + 2] = t4.z; Mreg[4 * k + 3] = t4.w;
            }
            #pragma unroll
            for (int k = 0; k < 8; ++k) {
                const float4 t4 = *(const float4*)(mnb + 32 + 4 * k);
                Nreg[4 * k] = t4.x; Nreg[4 * k + 1] = t4.y;
                Nreg[4 * k + 2] = t4.z; Nreg[4 * k + 3] = t4.w;
            }
        }

        // --- per-lane v, g; inclusive product scan P_u over the 32-group ---
        const float v_u = VGTc[gid][u];
        const float g_u = VGTc[8 + gid][u];
        float P = g_u;
        P = dpp_pmul<0x111>(P);          // row_shr:1 (identity 1.0)
        P = dpp_pmul<0x112>(P);          // row_shr:2
        P = dpp_pmul<0x114>(P);          // row_shr:4
        P = dpp_pmul<0x118>(P);          // row_shr:8
        {   // fold lower-16 total into upper 16 of each 32-group
            const int t15 = __builtin_amdgcn_ds_swizzle(__float_as_int(P), (15 << 5));
            const float pl = __int_as_float(t15);
            P = (u >= 16) ? P * pl : P;
        }
        const float Pm1  = P / g_u;      // exact-ish exclusive product
        const float invP = 1.0f / P;

        // --- a0/q0: acc = <s0,k_u>, accq = <s0,q_u> (broadcast reads) ---
        float acc = 0.f, accq = 0.f;
        #pragma unroll
        for (int a4 = 0; a4 < 16; ++a4) {
            const int L = 4 * (a4 ^ (u & 7));
            const float4 s4 = *(const float4*)&SROW[gid][4 * a4];
            const float4 k4 = *(const float4*)&KQc[u][L];
            const float4 q4 = *(const float4*)&KQc[u][64 + L];
            acc  = fmaf(s4.x, k4.x, fmaf(s4.y, k4.y,
                   fmaf(s4.z, k4.z, fmaf(s4.w, k4.w, acc))));
            accq = fmaf(s4.x, q4.x, fmaf(s4.y, q4.y,
                   fmaf(s4.z, q4.z, fmaf(s4.w, q4.w, accq))));
        }

        // --- 32-step forward substitution; supd accumulates the state update ---
        float2 supd = make_float2(0.f, 0.f);
#define SWEEP_STEP(T)                                                          \
        {                                                                      \
            const float e_ = (v_u - Pm1 * acc) * invP;                         \
            const int ei_ = __builtin_amdgcn_ds_swizzle(__float_as_int(e_),    \
                                                        ((T) << 5));           \
            const float eb_ = __int_as_float(ei_);                             \
            acc  = fmaf(eb_, Mreg[T], acc);                                    \
            accq = fmaf(eb_, Nreg[T], accq);                                   \
            const float2 kk_ = *(const float2*)&KQc[T][(2 * u) ^ (4 * ((T) & 7))]; \
            supd.x = fmaf(eb_, kk_.x, supd.x);                                 \
            supd.y = fmaf(eb_, kk_.y, supd.y);                                 \
        }
        SWEEP_STEP(0)  SWEEP_STEP(1)  SWEEP_STEP(2)  SWEEP_STEP(3)
        SWEEP_STEP(4)  SWEEP_STEP(5)  SWEEP_STEP(6)  SWEEP_STEP(7)
        SWEEP_STEP(8)  SWEEP_STEP(9)  SWEEP_STEP(10) SWEEP_STEP(11)
        SWEEP_STEP(12) SWEEP_STEP(13) SWEEP_STEP(14) SWEEP_STEP(15)
        SWEEP_STEP(16) SWEEP_STEP(17) SWEEP_STEP(18) SWEEP_STEP(19)
        SWEEP_STEP(20) SWEEP_STEP(21) SWEEP_STEP(22) SWEEP_STEP(23)
        SWEEP_STEP(24) SWEEP_STEP(25) SWEEP_STEP(26) SWEEP_STEP(27)
        SWEEP_STEP(28) SWEEP_STEP(29) SWEEP_STEP(30) SWEEP_STEP(31)
#undef SWEEP_STEP

        // --- state update (group-private) ---
        {
            const int p31 = __builtin_amdgcn_ds_swizzle(__float_as_int(P), (31 << 5));
            const float Pc = __int_as_float(p31);
            float2 sold = *(const float2*)&SROW[gid][2 * u];
            sold.x = Pc * (sold.x + supd.x);
            sold.y = Pc * (sold.y + supd.y);
            *(float2*)&SROW[gid][2 * u] = sold;
        }
        // --- output (lane u owns timestep c*32+u) with fused silu ---
        {
            const float oq = P * accq;
            const float y = oq * oq / (1.f + __expf(-oq));
            out[((size_t)(c * CH + u) * BATCH + b) * 64 + i] = y;
        }

        __syncthreads();
    }

    {   // final state
        const float2 sf = *(const float2*)&SROW[gid][2 * u];
        *(float2*)(Sfin + ((size_t)(b * 64 + i)) * 64 + 2 * u) = sf;
    }
}

// ================================ launch ================================
extern "C" void kernel_launch(void* const* d_in, const int* in_sizes, int n_in,
                              void* d_out, int out_size, void* d_ws, size_t ws_size,
                              hipStream_t stream) {
    const float* x  = (const float*)d_in[0];
    const float* S0 = (const float*)d_in[1];
    const float* Wk = (const float*)d_in[2];
    const float* Wv = (const float*)d_in[3];
    const float* Wq = (const float*)d_in[4];
    const float* Wb = (const float*)d_in[5];
    const float* bb = (const float*)d_in[6];

    float* out  = (float*)d_out;                               // [T][B][64]
    float* Sfin = out + (size_t)T_STEPS * BATCH * NSTATE;      // [B][64][64]

    float*    proj = (float*)d_ws;                                   // 33.55 MB
    float*    MN   = proj + (size_t)T_STEPS * BATCH * NFIELD;        // 8.39 MB
    _Float16* W16  = (_Float16*)(MN + (size_t)BATCH * NCHUNK * 32 * 64); // 0.5 MB

    prep_w16<<<128, 256, 0, stream>>>(Wk, Wv, Wq, Wb, W16);
    proj_mfma<<<(T_STEPS * BATCH) / PBM, 512, 0, stream>>>(x, W16, bb, proj);
    mn_prep<<<BATCH * NCHUNK, 256, 0, stream>>>(proj, MN);
    scan_kernel<<<(BATCH * NSTATE) / 8, 256, 0, stream>>>(proj, MN, S0, out, Sfin);
}

// Round 10
// 385.597 us; speedup vs baseline: 1.1558x; 1.0945x over previous
//
#include <hip/hip_runtime.h>
#include <math.h>

#define T_STEPS 2048
#define BATCH   16
#define DIM     1024
#define NSTATE  64
#define NFIELD  256                      // per (t,b): [k_norm|v|q|g] x 64
#define PROJ_TSTRIDE (BATCH * NFIELD)    // 4096 floats per t
static constexpr float EPS = 1e-6f;

#define AS1 __attribute__((address_space(1)))
#define AS3 __attribute__((address_space(3)))

typedef _Float16 f16x8 __attribute__((ext_vector_type(8)));
typedef _Float16 f16x4 __attribute__((ext_vector_type(4)));
typedef _Float16 f16x2 __attribute__((ext_vector_type(2)));
typedef float    f32x4 __attribute__((ext_vector_type(4)));

// ===================== cross-lane helpers =====================
// multiplicative DPP step for inclusive product scan (identity = 1.0)
template <int CTRL, int RMASK>
__device__ __forceinline__ float dpp_pmul(float x) {
    int yi = __builtin_amdgcn_update_dpp(0x3f800000, __float_as_int(x),
                                         CTRL, RMASK, 0xF, false);
    return x * __int_as_float(yi);
}
__device__ __forceinline__ float rdlane(float x, int l) {
    return __int_as_float(__builtin_amdgcn_readlane(__float_as_int(x), l));
}

// ========================= projection GEMM (fp16 MFMA) =========================
// (unchanged from round-6 passing version)

#define PBM   128
#define KSTEP 64
#define NKS   (DIM / KSTEP)   // 16

__global__ __launch_bounds__(256) void prep_w16(
    const float* __restrict__ Wk, const float* __restrict__ Wv,
    const float* __restrict__ Wq, const float* __restrict__ Wb,
    _Float16* __restrict__ W16)
{
    const int flat = blockIdx.x * 256 + threadIdx.x;   // 16*32*64 = 32768
    const int lane = flat & 63;
    const int st   = (flat >> 6) & 31;
    const int ks   = flat >> 11;
    const int cg = st & 15, kc2 = st >> 4;
    const int col = cg * 16 + (lane & 15);
    const int field = col >> 6, wrow = col & 63;
    const float* Wf = (field == 0 ? Wk : field == 1 ? Wv : field == 2 ? Wq : Wb);
    const float* src = Wf + (size_t)wrow * DIM + ks * 64 + kc2 * 32 + (lane >> 4) * 8;
    const float4 a = *(const float4*)(src);
    const float4 b = *(const float4*)(src + 4);
    f16x8 r;
    r[0] = (_Float16)a.x; r[1] = (_Float16)a.y; r[2] = (_Float16)a.z; r[3] = (_Float16)a.w;
    r[4] = (_Float16)b.x; r[5] = (_Float16)b.y; r[6] = (_Float16)b.z; r[7] = (_Float16)b.w;
    *(f16x8*)(W16 + (size_t)flat * 8) = r;
}

__global__ __launch_bounds__(512, 1) void proj_mfma(
    const float* __restrict__ x, const _Float16* __restrict__ W16,
    const float* __restrict__ bb, float* __restrict__ proj)
{
    __shared__ _Float16 Asub[2][16][64][8];   // 16KB/buf
    __shared__ _Float16 Bsub[2][32][64][8];   // 32KB/buf

    const int tid = threadIdx.x;
    const int w = tid >> 6, wl = tid & 63;
    const int wm = w >> 2, wn = w & 3;
    const int l15 = wl & 15, lr = wl >> 4;
    const size_t mbase = (size_t)blockIdx.x * PBM;

    _Float16* const abase = &Asub[0][0][0][0];
    _Float16* const bbase = &Bsub[0][0][0][0];

    const float* asrc[4];
    int aoff[4];
    #pragma unroll
    for (int it = 0; it < 4; ++it) {
        const int fid = it * 512 + tid;
        const int row = fid >> 4, kq = (fid & 15) * 4;
        asrc[it] = x + (mbase + row) * (size_t)DIM + kq;
        aoff[it] = ((kq >> 5) * 8 + (row >> 4)) * 512
                 + ((row & 15) + ((kq >> 3) & 3) * 16) * 8
                 + (kq & 7);
    }
    const _Float16* bsrc[4];
    int boff[4];
    #pragma unroll
    for (int m = 0; m < 4; ++m) {
        const int st = w * 4 + m;
        bsrc[m] = W16 + ((size_t)st * 64 + wl) * 8;
        boff[m] = st * 512;
    }

    auto stageB = [&](int ks, int buf) {
        #pragma unroll
        for (int m = 0; m < 4; ++m) {
            const _Float16* g = bsrc[m] + (size_t)ks * 16384;
            void* lp = (char*)bbase + (size_t)(buf * 16384 + boff[m]) * 2;
            __builtin_amdgcn_global_load_lds((const AS1 void*)g, (AS3 void*)lp, 16, 0, 0);
        }
    };

    float4 h0[4], h1[4];
    auto loadA = [&](int ks, float4* h) {
        #pragma unroll
        for (int it = 0; it < 4; ++it)
            h[it] = *(const float4*)(asrc[it] + ks * KSTEP);
    };
    auto writeA = [&](const float4* h, int buf) {
        #pragma unroll
        for (int it = 0; it < 4; ++it) {
            f16x4 v;
            v[0] = (_Float16)h[it].x; v[1] = (_Float16)h[it].y;
            v[2] = (_Float16)h[it].z; v[3] = (_Float16)h[it].w;
            *(f16x4*)(abase + buf * 8192 + aoff[it]) = v;
        }
    };

    f32x4 acc[4][4] = {};

    loadA(0, h0);
    stageB(0, 0);
    loadA(1, h1);
    writeA(h0, 0);
    __syncthreads();

    #pragma unroll
    for (int ks = 0; ks < NKS; ++ks) {
        const int buf = ks & 1;
        if (ks + 1 < NKS) stageB(ks + 1, buf ^ 1);
        if (ks + 2 < NKS) loadA(ks + 2, (ks & 1) ? h1 : h0);

        #pragma unroll
        for (int kc = 0; kc < 2; ++kc) {
            f16x8 af[4], bf[4];
            #pragma unroll
            for (int mf = 0; mf < 4; ++mf)
                af[mf] = *(const f16x8*)&Asub[buf][kc * 8 + wm * 4 + mf][wl][0];
            #pragma unroll
            for (int nf = 0; nf < 4; ++nf)
                bf[nf] = *(const f16x8*)&Bsub[buf][kc * 16 + wn * 4 + nf][wl][0];
            #pragma unroll
            for (int mf = 0; mf < 4; ++mf)
                #pragma unroll
                for (int nf = 0; nf < 4; ++nf)
                    acc[mf][nf] = __builtin_amdgcn_mfma_f32_16x16x32_f16(
                        af[mf], bf[nf], acc[mf][nf], 0, 0, 0);
        }

        if (ks + 1 < NKS) writeA((ks & 1) ? h0 : h1, buf ^ 1);
        __syncthreads();
    }

    if (wn == 0) {                       // k field: row-normalize over 64 cols
        #pragma unroll
        for (int mf = 0; mf < 4; ++mf) {
            f32x4 s = acc[mf][0] * acc[mf][0];
            #pragma unroll
            for (int nf = 1; nf < 4; ++nf) s += acc[mf][nf] * acc[mf][nf];
            #pragma unroll
            for (int r = 0; r < 4; ++r) {
                float t = s[r];
                t += __shfl_xor(t, 1); t += __shfl_xor(t, 2);
                t += __shfl_xor(t, 4); t += __shfl_xor(t, 8);
                const float sc = 1.f / (sqrtf(t) + EPS);
                #pragma unroll
                for (int nf = 0; nf < 4; ++nf) acc[mf][nf][r] *= sc;
            }
        }
    }
    if (wn == 3) {                       // beta field: sigmoid(acc + bias)
        #pragma unroll
        for (int nf = 0; nf < 4; ++nf) {
            const float bv = bb[nf * 16 + l15];
            #pragma unroll
            for (int mf = 0; mf < 4; ++mf)
                #pragma unroll
                for (int r = 0; r < 4; ++r)
                    acc[mf][nf][r] = 1.f / (1.f + __expf(-(acc[mf][nf][r] + bv)));
        }
    }

    #pragma unroll
    for (int mf = 0; mf < 4; ++mf)
        #pragma unroll
        for (int r = 0; r < 4; ++r) {
            float* dst = proj + (mbase + wm * 64 + mf * 16 + lr * 4 + r) * NFIELD
                              + wn * 64 + l15;
            dst[0]  = acc[mf][0][r];
            dst[16] = acc[mf][1][r];
            dst[32] = acc[mf][2][r];
            dst[48] = acc[mf][3][r];
        }
}

// ============================ M/N gram precompute ============================
// Per (b, ch): for t,u in [0,64): M[t][u] = <k_t,k_u> if u>t else 0
//                                 N[t][u] = <k_t,q_u> if u>=t else 0
// Packed fp16 pairs: MNg[((b*32+ch)*64 + t)*128 + 2u] = {M, N}.

#define CH 64
#define NCHUNK (T_STEPS / CH)   // 32

__global__ __launch_bounds__(256) void mn_prep(
    const float* __restrict__ proj, _Float16* __restrict__ MNg)
{
    __shared__ float K[64][68], Q[64][68];
    const int bch = blockIdx.x;            // b*32 + ch
    const int bb2 = bch >> 5, ch = bch & 31;
    const int tid = threadIdx.x;

    #pragma unroll
    for (int it = 0; it < 8; ++it) {       // 2048 float4 slots, coalesced
        const int s = it * 256 + tid;
        const int row = s >> 5, half = (s >> 4) & 1, idx = s & 15;
        const float* src = proj + ((size_t)(ch * 64 + row) * BATCH + bb2) * NFIELD
                         + (half ? 128 : 0) + idx * 4;
        const float4 v4 = *(const float4*)src;
        if (half == 0) *(float4*)&K[row][idx * 4] = v4;
        else           *(float4*)&Q[row][idx * 4] = v4;
    }
    __syncthreads();

    const int t0 = (tid >> 4) * 4, u0 = (tid & 15) * 4;
    float m4[4][4] = {}, n4[4][4] = {};
    #pragma unroll
    for (int j4 = 0; j4 < 16; ++j4) {
        float4 kt[4], ku[4], qu[4];
        #pragma unroll
        for (int r = 0; r < 4; ++r) {
            kt[r] = *(const float4*)&K[t0 + r][4 * j4];
            ku[r] = *(const float4*)&K[u0 + r][4 * j4];
            qu[r] = *(const float4*)&Q[u0 + r][4 * j4];
        }
        #pragma unroll
        for (int a2 = 0; a2 < 4; ++a2)
            #pragma unroll
            for (int c2 = 0; c2 < 4; ++c2) {
                m4[a2][c2] = fmaf(kt[a2].x, ku[c2].x, fmaf(kt[a2].y, ku[c2].y,
                             fmaf(kt[a2].z, ku[c2].z, fmaf(kt[a2].w, ku[c2].w, m4[a2][c2]))));
                n4[a2][c2] = fmaf(kt[a2].x, qu[c2].x, fmaf(kt[a2].y, qu[c2].y,
                             fmaf(kt[a2].z, qu[c2].z, fmaf(kt[a2].w, qu[c2].w, n4[a2][c2]))));
            }
    }
    _Float16* dst = MNg + (size_t)bch * 64 * 128;
    #pragma unroll
    for (int a2 = 0; a2 < 4; ++a2) {
        const int t = t0 + a2;
        #pragma unroll
        for (int c2 = 0; c2 < 4; ++c2) {
            const int uu = u0 + c2;
            f16x2 val;
            val[0] = (_Float16)((uu > t)  ? m4[a2][c2] : 0.f);
            val[1] = (_Float16)((uu >= t) ? n4[a2][c2] : 0.f);
            *(f16x2*)&dst[(size_t)t * 128 + 2 * uu] = val;
        }
    }
}

// ============================ scan v12: readlane forward-substitution ============================
// One wave per state row; lane u = timestep u (of the 64-step chunk) AND state
// column u. Rescaled frame: e_t = d_t/P_t; acc_u carries <s0,k_u> + sum e M;
// broadcast of e_T via v_readlane -> SGPR (no DS op on the serial chain):
//   step T: e = c1 - c2*acc ; se = readlane(e,T) ;
//           acc += se*M[T][u] ; accq += se*N[T][u] ; supd += se*k_T[u]
// out_u = P_u*accq (exact); S_new[u] = P_63*(s0[u]+supd[u]) (exact).
// P via 6-op DPP multiplicative wave scan (LLVM AtomicOptimizer pattern).

__global__ __launch_bounds__(256, 1) void scan_kernel(
    const float* __restrict__ proj,     // [T][B][256]
    const _Float16* __restrict__ MNg,   // [b][ch][t][2u]={M,N} fp16
    const float* __restrict__ S0,       // [B][64][64]
    float* __restrict__ out,            // [T][B][64]
    float* __restrict__ Sfin)           // [B][64][64]
{
    __shared__ float    KQ[2][CH][128];   // [t][0:64)=k, [64:128)=q   64 KB
    __shared__ _Float16 MNh[2][CH][128];  // [t][2u]={M,N}             32 KB
    __shared__ float    VG[2][CH][8];     // [t][{v rows, g rows}]      4 KB
    __shared__ float    OUTb[2][CH][4];   //                            2 KB
    __shared__ float    SROW[4][64];      // per-wave state row         1 KB

    const int tid = threadIdx.x;
    const int w = tid >> 6, u = tid & 63;      // wave = row, lane = timestep/col
    const int b  = blockIdx.x >> 4;
    const int i0 = (blockIdx.x & 15) * 4;
    const int i  = i0 + w;

    float S = S0[((size_t)(b * 64 + i)) * 64 + u];
    SROW[w][u] = S;

    const float* pb = proj + (size_t)b * NFIELD;
    const _Float16* mnb = MNg + (size_t)b * NCHUNK * CH * 128;

    // --- DMA lane maps (constant per lane) ---
    const int kq_dw = (u & 31) * 4;
    const int kq_f  = (kq_dw < 64) ? kq_dw : kq_dw + 64;   // k: 0-63, q: 128-191
    const int kq_t  = u >> 5;
    const int mn_t  = u >> 4;
    const int mn_by = (u & 15) * 16;
    const int vg_t  = u >> 3;
    const int vg_fi = u & 7;
    const int vg_f  = (vg_fi < 4) ? (64 + i0 + vg_fi) : (192 + i0 + vg_fi - 4);

    auto stage = [&](int c, int nb) {
        const float* cbase = pb + (size_t)c * CH * PROJ_TSTRIDE;
        #pragma unroll
        for (int m = 0; m < 8; ++m) {                   // KQ: 32 KB, 32 insts
            const int n = w * 8 + m;
            const float* g = cbase + (size_t)(2 * n + kq_t) * PROJ_TSTRIDE + kq_f;
            void* lp = (char*)&KQ[nb][0][0] + n * 1024;
            __builtin_amdgcn_global_load_lds((const AS1 void*)g, (AS3 void*)lp, 16, 0, 0);
        }
        const char* mnc = (const char*)(mnb + (size_t)c * CH * 128);
        #pragma unroll
        for (int m = 0; m < 4; ++m) {                   // MN: 16 KB, 16 insts
            const int n = w * 4 + m;
            const char* g = mnc + (size_t)(4 * n + mn_t) * 256 + mn_by;
            void* lp = (char*)&MNh[nb][0][0] + n * 1024;
            __builtin_amdgcn_global_load_lds((const AS1 void*)g, (AS3 void*)lp, 16, 0, 0);
        }
        #pragma unroll
        for (int m = 0; m < 2; ++m) {                   // VG: 2 KB, 8 insts
            const int p = w * 2 + m;
            const float* g = cbase + (size_t)(p * 8 + vg_t) * PROJ_TSTRIDE + vg_f;
            void* lp = (char*)&VG[nb][0][0] + p * 256;
            __builtin_amdgcn_global_load_lds((const AS1 void*)g, (AS3 void*)lp, 4, 0, 0);
        }
    };

    stage(0, 0);
    __syncthreads();

    for (int c = 0; c < NCHUNK; ++c) {
        const int cb2 = c & 1;
        if (c + 1 < NCHUNK) stage(c + 1, cb2 ^ 1);

        // --- per-lane v,g; inclusive product scan over 64 lanes ---
        const float v_u = VG[cb2][u][w];
        const float g_u = VG[cb2][u][4 + w];
        float P = g_u;
        P = dpp_pmul<0x111, 0xF>(P);     // row_shr:1
        P = dpp_pmul<0x112, 0xF>(P);     // row_shr:2
        P = dpp_pmul<0x114, 0xF>(P);     // row_shr:4
        P = dpp_pmul<0x118, 0xF>(P);     // row_shr:8
        P = dpp_pmul<0x142, 0xA>(P);     // row_bcast15 -> lanes 16-31, 48-63
        P = dpp_pmul<0x143, 0xC>(P);     // row_bcast31 -> lanes 32-63
        const float invP = __builtin_amdgcn_rcpf(P);
        const float c1 = v_u * invP;
        const float c2 = __builtin_amdgcn_rcpf(g_u);   // = Pm1*invP

        // --- a0/q0: acc = <s0,k_u>, accq = <s0,q_u> (XOR-swizzled, conflict-free) ---
        float acc = 0.f, accq = 0.f;
        #pragma unroll
        for (int j4 = 0; j4 < 16; ++j4) {
            const int Cg = 4 * (j4 ^ (u & 15));
            const float4 s4 = *(const float4*)&SROW[w][Cg];
            const float4 k4 = *(const float4*)&KQ[cb2][u][Cg];
            const float4 q4 = *(const float4*)&KQ[cb2][u][64 + Cg];
            acc  = fmaf(s4.x, k4.x, fmaf(s4.y, k4.y,
                   fmaf(s4.z, k4.z, fmaf(s4.w, k4.w, acc))));
            accq = fmaf(s4.x, q4.x, fmaf(s4.y, q4.y,
                   fmaf(s4.z, q4.z, fmaf(s4.w, q4.w, accq))));
        }

        // --- 64-step forward substitution; broadcast via readlane (no DS) ---
        float supd = 0.f;
        #pragma unroll
        for (int T = 0; T < CH; ++T) {
            const float e  = fmaf(-c2, acc, c1);
            const float se = rdlane(e, T);
            const f16x2 mn = *(const f16x2*)&MNh[cb2][T][2 * u];
            const float kT = KQ[cb2][T][u];
            acc  = fmaf(se, (float)mn[0], acc);
            accq = fmaf(se, (float)mn[1], accq);
            supd = fmaf(se, kT, supd);
        }

        // --- epilogue: state update + output (exact rescale) ---
        const float Pc = rdlane(P, 63);
        S = Pc * (S + supd);
        SROW[w][u] = S;                   // wave-private
        const float oq = P * accq;
        OUTb[cb2][u][w] = oq * oq / (1.f + __expf(-oq));   // fused silu

        __syncthreads();                  // DMA drained + OUTb visible

        {   // cooperative coalesced-ish store: 4 rows x 16B per t
            const int t = tid >> 2, col = tid & 3;
            out[((size_t)(c * CH + t) * BATCH + b) * 64 + i0 + col] = OUTb[cb2][t][col];
        }
    }

    Sfin[((size_t)(b * 64 + i)) * 64 + u] = S;
}

// ================================ launch ================================
extern "C" void kernel_launch(void* const* d_in, const int* in_sizes, int n_in,
                              void* d_out, int out_size, void* d_ws, size_t ws_size,
                              hipStream_t stream) {
    const float* x  = (const float*)d_in[0];
    const float* S0 = (const float*)d_in[1];
    const float* Wk = (const float*)d_in[2];
    const float* Wv = (const float*)d_in[3];
    const float* Wq = (const float*)d_in[4];
    const float* Wb = (const float*)d_in[5];
    const float* bb = (const float*)d_in[6];

    float* out  = (float*)d_out;                               // [T][B][64]
    float* Sfin = out + (size_t)T_STEPS * BATCH * NSTATE;      // [B][64][64]

    float*    proj = (float*)d_ws;                                    // 33.55 MB
    _Float16* MNg  = (_Float16*)(proj + (size_t)T_STEPS * BATCH * NFIELD); // 8.39 MB
    _Float16* W16  = MNg + (size_t)BATCH * NCHUNK * CH * 128;         // 0.5 MB

    prep_w16<<<128, 256, 0, stream>>>(Wk, Wv, Wq, Wb, W16);
    proj_mfma<<<(T_STEPS * BATCH) / PBM, 512, 0, stream>>>(x, W16, bb, proj);
    mn_prep<<<BATCH * NCHUNK, 256, 0, stream>>>(proj, MNg);
    scan_kernel<<<BATCH * 16, 256, 0, stream>>>(proj, MNg, S0, out, Sfin);
}